// Round 3
// baseline (787.736 us; speedup 1.0000x reference)
//
#include <hip/hip_runtime.h>
#include <math.h>

#define NB 8192
#define H 1024
#define HH 512
#define NEXP 16
#define NTILES 272          // max sum of per-expert ceil(cnt/32)
#define AMBIG_THR 0.05f

// MFMA 16x16x32 bf16 fragments
typedef __attribute__((ext_vector_type(8))) short bfrag;
typedef __attribute__((ext_vector_type(4))) float f4;

__device__ __forceinline__ f4 MF(bfrag a, bfrag b, f4 c) {
    return __builtin_amdgcn_mfma_f32_16x16x32_bf16(a, b, c, 0, 0, 0);
}
__device__ __forceinline__ unsigned short f2bf(float f) {  // RNE fp32->bf16
    unsigned u = __float_as_uint(f);
    u += 0x7fff + ((u >> 16) & 1);
    return (unsigned short)(u >> 16);
}

__global__ __launch_bounds__(64) void zero_kernel(int* counts, int* ambig_cnt) {
    if (threadIdx.x < NEXP) counts[threadIdx.x] = 0;
    if (threadIdx.x == 0) ambig_cnt[0] = 0;
}

__global__ __launch_bounds__(256) void convert_plain(
    const float* __restrict__ src, unsigned short* __restrict__ dst, int n4)
{
    int i = blockIdx.x * 256 + threadIdx.x;
    if (i >= n4) return;
    float4 v = ((const float4*)src)[i];
    ushort4 h;
    h.x = f2bf(v.x); h.y = f2bf(v.y); h.z = f2bf(v.z); h.w = f2bf(v.w);
    ((ushort4*)dst)[i] = h;
}

// ---- gating GEMM1: x1[8192][512] = relu(q @ w1^T + b1), bf16 in/out ----
// grid (256, 4): 32 rows x 128 cols per block; wave owns 32 cols.
__global__ __launch_bounds__(256, 4) void g1_kernel(
    const unsigned short* __restrict__ qb, const unsigned short* __restrict__ w1b,
    const float* __restrict__ b1, unsigned short* __restrict__ x1)
{
    const int t = threadIdx.x, wave = t >> 6, lane = t & 63;
    const int quad = lane >> 4, l16 = lane & 15;
    const int row0 = blockIdx.x * 32;
    const int colbase = blockIdx.y * 128 + wave * 32;
    const f4 z4 = {0.f, 0.f, 0.f, 0.f};
    f4 acc[2][2] = {{z4, z4}, {z4, z4}};

    const size_t ar0 = (size_t)(row0 + l16) * H + quad * 8;
    const size_t ar1 = ar0 + (size_t)16 * H;
    const size_t br0 = (size_t)(colbase + l16) * H + quad * 8;
    #pragma unroll 2
    for (int kk = 0; kk < H; kk += 32) {
        bfrag a0 = *(const bfrag*)(qb + ar0 + kk);
        bfrag a1 = *(const bfrag*)(qb + ar1 + kk);
        bfrag bb0 = *(const bfrag*)(w1b + br0 + kk);
        bfrag bb1 = *(const bfrag*)(w1b + br0 + (size_t)16 * H + kk);
        acc[0][0] = MF(a0, bb0, acc[0][0]); acc[1][0] = MF(a1, bb0, acc[1][0]);
        acc[0][1] = MF(a0, bb1, acc[0][1]); acc[1][1] = MF(a1, bb1, acc[1][1]);
    }
    #pragma unroll
    for (int cb = 0; cb < 2; ++cb) {
        int col = colbase + cb * 16 + l16;
        float bias = b1[col];
        #pragma unroll
        for (int rb = 0; rb < 2; ++rb)
            #pragma unroll
            for (int i = 0; i < 4; ++i) {
                int row = rb * 16 + quad * 4 + i;
                x1[(size_t)(row0 + row) * HH + col] = f2bf(fmaxf(acc[rb][cb][i] + bias, 0.f));
            }
    }
}

// ---- logits + argmax + gate + ambiguity flag. grid 256 (32 rows/block). ----
__global__ __launch_bounds__(256) void logits_kernel(
    const unsigned short* __restrict__ x1, const unsigned short* __restrict__ w3b,
    const float* __restrict__ b3,
    int* __restrict__ top1, float* __restrict__ gval,
    int* __restrict__ ambig_rows, int* __restrict__ ambig_cnt)
{
    __shared__ float lgp[4][32][NEXP];
    const int t = threadIdx.x, wave = t >> 6, lane = t & 63;
    const int quad = lane >> 4, l16 = lane & 15;
    const int row0 = blockIdx.x * 32;
    const f4 z4 = {0.f, 0.f, 0.f, 0.f};

    f4 l0 = z4, l1 = z4;
    const size_t ar0 = (size_t)(row0 + l16) * HH + quad * 8;
    const size_t ar1 = ar0 + (size_t)16 * HH;
    const size_t br = (size_t)l16 * HH + quad * 8;
    #pragma unroll
    for (int ks = 0; ks < 4; ++ks) {
        int kk = wave * 128 + ks * 32;
        bfrag a0 = *(const bfrag*)(x1 + ar0 + kk);
        bfrag a1 = *(const bfrag*)(x1 + ar1 + kk);
        bfrag b  = *(const bfrag*)(w3b + br + kk);
        l0 = MF(a0, b, l0);
        l1 = MF(a1, b, l1);
    }
    #pragma unroll
    for (int i = 0; i < 4; ++i) {
        lgp[wave][quad * 4 + i][l16] = l0[i];
        lgp[wave][16 + quad * 4 + i][l16] = l1[i];
    }
    __syncthreads();

    if (t < 32) {
        float lg[NEXP];
        #pragma unroll
        for (int m = 0; m < NEXP; ++m)
            lg[m] = lgp[0][t][m] + lgp[1][t][m] + lgp[2][t][m] + lgp[3][t][m] + b3[m];
        float best = lg[0], second = -3.4e38f; int bi = 0;
        #pragma unroll
        for (int m = 1; m < NEXP; ++m) {
            float v = lg[m];
            if (v > best) { second = best; best = v; bi = m; }
            else if (v > second) second = v;
        }
        float se = 0.f;
        #pragma unroll
        for (int m = 0; m < NEXP; ++m) se += expf(lg[m] - best);
        int grow = row0 + t;
        top1[grow] = bi;
        gval[grow] = 1.f / se;
        if (best - second < AMBIG_THR) {
            int pos = atomicAdd(ambig_cnt, 1);
            if (pos < NB) ambig_rows[pos] = grow;
        }
    }
}

// ---- exact fp32 gating recompute for ambiguous rows. grid 256, row/block. ----
__global__ __launch_bounds__(256) void fixup_kernel(
    const float* __restrict__ q, const float* __restrict__ w1, const float* __restrict__ b1,
    const float* __restrict__ w3, const float* __restrict__ b3,
    const int* __restrict__ ambig_rows, const int* __restrict__ ambig_cnt,
    int* __restrict__ top1, float* __restrict__ gval)
{
    __shared__ float qrow[H];
    __shared__ float x1[HH];
    __shared__ float lg[NEXP];
    const int t = threadIdx.x;
    int nn = *ambig_cnt; if (nn > NB) nn = NB;
    for (int ii = blockIdx.x; ii < nn; ii += 256) {
        int row = ambig_rows[ii];
        for (int j = t; j < H / 4; j += 256)
            ((float4*)qrow)[j] = ((const float4*)(q + (size_t)row * H))[j];
        __syncthreads();
        for (int c = t; c < HH; c += 256) {
            const float4* wv = (const float4*)(w1 + (size_t)c * H);
            const float4* qv = (const float4*)qrow;
            float s = 0.f;
            for (int k = 0; k < H / 4; ++k) {
                float4 a = qv[k], b = wv[k];
                s += a.x * b.x + a.y * b.y + a.z * b.z + a.w * b.w;
            }
            x1[c] = fmaxf(s + b1[c], 0.f);
        }
        __syncthreads();
        if (t < NEXP) {
            float s = 0.f;
            const float* wr = w3 + (size_t)t * HH;
            for (int k = 0; k < HH; ++k) s += x1[k] * wr[k];
            lg[t] = s + b3[t];
        }
        __syncthreads();
        if (t == 0) {
            float best = lg[0]; int bi = 0;
            for (int m = 1; m < NEXP; ++m) if (lg[m] > best) { best = lg[m]; bi = m; }
            float se = 0.f;
            for (int m = 0; m < NEXP; ++m) se += expf(lg[m] - best);
            top1[row] = bi;
            gval[row] = 1.f / se;
        }
        __syncthreads();
    }
}

__global__ __launch_bounds__(256) void count_kernel(
    const int* __restrict__ top1, int* __restrict__ counts)
{
    int b = blockIdx.x * 256 + threadIdx.x;
    atomicAdd(&counts[top1[b]], 1);
}

// offsets + tile map (tile -> expert, start position, end position)
__global__ __launch_bounds__(64) void offsets_kernel(
    const int* __restrict__ counts, int* __restrict__ offsets, int* __restrict__ bpos,
    int* __restrict__ tm_e, int* __restrict__ tm_p, int* __restrict__ tm_end)
{
    if (threadIdx.x == 0) {
        int run = 0;
        for (int e = 0; e < NEXP; ++e) { offsets[e] = run; bpos[e] = run; run += counts[e]; }
        int tile = 0;
        for (int e = 0; e < NEXP; ++e) {
            int beg = offsets[e], end = beg + counts[e];
            for (int p = beg; p < end; p += 32) {
                tm_e[tile] = e; tm_p[tile] = p; tm_end[tile] = end; ++tile;
            }
        }
        for (; tile < NTILES; ++tile) tm_e[tile] = -1;
    }
}

__global__ __launch_bounds__(256) void scatter_kernel(
    const int* __restrict__ top1, int* __restrict__ bpos, int* __restrict__ brows)
{
    int b = blockIdx.x * 256 + threadIdx.x;
    int e = top1[b];
    int pos = atomicAdd(&bpos[e], 1);
    brows[pos] = b;
}

// ---- expert GEMM1: h[pos][512] = relu(q[row] @ w1[e]^T + b1[e]) ----
// grid (NTILES, 4): 32 sorted rows x 128 cols.
__global__ __launch_bounds__(256, 4) void exp1_kernel(
    const unsigned short* __restrict__ qb, const unsigned short* __restrict__ ew1b,
    const float* __restrict__ eb1,
    const int* __restrict__ tm_e, const int* __restrict__ tm_p, const int* __restrict__ tm_end,
    const int* __restrict__ brows, unsigned short* __restrict__ h)
{
    const int e = tm_e[blockIdx.x];
    if (e < 0) return;
    const int p0 = tm_p[blockIdx.x], end = tm_end[blockIdx.x];

    __shared__ int rrow[32];
    const int t = threadIdx.x, wave = t >> 6, lane = t & 63;
    const int quad = lane >> 4, l16 = lane & 15;
    if (t < 32) {
        int pos = p0 + t; if (pos >= end) pos = end - 1;
        rrow[t] = brows[pos];
    }
    __syncthreads();

    const int colbase = blockIdx.y * 128 + wave * 32;
    const unsigned short* w1p = ew1b + (size_t)e * HH * H;
    const f4 z4 = {0.f, 0.f, 0.f, 0.f};
    f4 acc[2][2] = {{z4, z4}, {z4, z4}};

    const size_t ar0 = (size_t)rrow[l16] * H + quad * 8;
    const size_t ar1 = (size_t)rrow[16 + l16] * H + quad * 8;
    const size_t br0 = (size_t)(colbase + l16) * H + quad * 8;
    #pragma unroll 2
    for (int kk = 0; kk < H; kk += 32) {
        bfrag a0 = *(const bfrag*)(qb + ar0 + kk);
        bfrag a1 = *(const bfrag*)(qb + ar1 + kk);
        bfrag bb0 = *(const bfrag*)(w1p + br0 + kk);
        bfrag bb1 = *(const bfrag*)(w1p + br0 + (size_t)16 * H + kk);
        acc[0][0] = MF(a0, bb0, acc[0][0]); acc[1][0] = MF(a1, bb0, acc[1][0]);
        acc[0][1] = MF(a0, bb1, acc[0][1]); acc[1][1] = MF(a1, bb1, acc[1][1]);
    }
    #pragma unroll
    for (int cb = 0; cb < 2; ++cb) {
        int col = colbase + cb * 16 + l16;
        float bias = eb1[e * HH + col];
        #pragma unroll
        for (int rb = 0; rb < 2; ++rb)
            #pragma unroll
            for (int i = 0; i < 4; ++i) {
                int row = rb * 16 + quad * 4 + i;
                if (p0 + row < end)   // don't clobber the next expert's positions
                    h[(size_t)(p0 + row) * HH + col] = f2bf(fmaxf(acc[rb][cb][i] + bias, 0.f));
            }
    }
}

// ---- expert GEMM2: v[row][1024] = h @ w2[e]^T + b2[e]; psum[row][chunk]=sum v^2 ----
// grid (NTILES, 8): 32 sorted rows x 128 cols.
__global__ __launch_bounds__(256, 4) void exp2_kernel(
    const unsigned short* __restrict__ h, const unsigned short* __restrict__ ew2b,
    const float* __restrict__ eb2,
    const int* __restrict__ tm_e, const int* __restrict__ tm_p, const int* __restrict__ tm_end,
    const int* __restrict__ brows,
    float* __restrict__ vout, float* __restrict__ psum)
{
    const int e = tm_e[blockIdx.x];
    if (e < 0) return;
    const int p0 = tm_p[blockIdx.x], end = tm_end[blockIdx.x];

    __shared__ int rrow[32];
    __shared__ float rqp[4][32];
    const int t = threadIdx.x, wave = t >> 6, lane = t & 63;
    const int quad = lane >> 4, l16 = lane & 15;
    if (t < 32) {
        int pos = p0 + t; if (pos >= end) pos = end - 1;
        rrow[t] = brows[pos];
    }
    __syncthreads();

    const int colbase = blockIdx.y * 128 + wave * 32;
    const unsigned short* w2p = ew2b + (size_t)e * H * HH;
    const f4 z4 = {0.f, 0.f, 0.f, 0.f};
    f4 acc[2][2] = {{z4, z4}, {z4, z4}};

    int hp0 = p0 + l16;      if (hp0 >= end) hp0 = end - 1;
    int hp1 = p0 + 16 + l16; if (hp1 >= end) hp1 = end - 1;
    const size_t ar0 = (size_t)hp0 * HH + quad * 8;
    const size_t ar1 = (size_t)hp1 * HH + quad * 8;
    const size_t br0 = (size_t)(colbase + l16) * HH + quad * 8;
    #pragma unroll 2
    for (int kk = 0; kk < HH; kk += 32) {
        bfrag a0 = *(const bfrag*)(h + ar0 + kk);
        bfrag a1 = *(const bfrag*)(h + ar1 + kk);
        bfrag bb0 = *(const bfrag*)(w2p + br0 + kk);
        bfrag bb1 = *(const bfrag*)(w2p + br0 + (size_t)16 * HH + kk);
        acc[0][0] = MF(a0, bb0, acc[0][0]); acc[1][0] = MF(a1, bb0, acc[1][0]);
        acc[0][1] = MF(a0, bb1, acc[0][1]); acc[1][1] = MF(a1, bb1, acc[1][1]);
    }

    float rs0[4] = {0.f, 0.f, 0.f, 0.f}, rs1[4] = {0.f, 0.f, 0.f, 0.f};
    #pragma unroll
    for (int cb = 0; cb < 2; ++cb) {
        int col = colbase + cb * 16 + l16;
        float bias = eb2[e * H + col];
        #pragma unroll
        for (int i = 0; i < 4; ++i) {
            float v0 = acc[0][cb][i] + bias;
            float v1 = acc[1][cb][i] + bias;
            int r0 = quad * 4 + i, r1 = 16 + quad * 4 + i;
            vout[(size_t)rrow[r0] * H + col] = v0;
            vout[(size_t)rrow[r1] * H + col] = v1;
            rs0[i] += v0 * v0;
            rs1[i] += v1 * v1;
        }
    }
    #pragma unroll
    for (int i = 0; i < 4; ++i) {
        float s0 = rs0[i], s1 = rs1[i];
        #pragma unroll
        for (int off = 8; off; off >>= 1) {
            s0 += __shfl_xor(s0, off, 16);
            s1 += __shfl_xor(s1, off, 16);
        }
        if (l16 == 0) {
            rqp[wave][quad * 4 + i] = s0;
            rqp[wave][16 + quad * 4 + i] = s1;
        }
    }
    __syncthreads();
    if (t < 32)
        psum[(size_t)rrow[t] * 8 + blockIdx.y] = rqp[0][t] + rqp[1][t] + rqp[2][t] + rqp[3][t];
}

__global__ __launch_bounds__(256) void scale_kernel(
    const float* __restrict__ psum, const float* __restrict__ gval, float* __restrict__ scale)
{
    int r = blockIdx.x * 256 + threadIdx.x;
    float s = 0.f;
    #pragma unroll
    for (int j = 0; j < 8; ++j) s += psum[(size_t)r * 8 + j];
    float n = sqrtf(s);
    float g = gval[r];
    scale[r] = g / fmaxf(g * n, 1e-6f);
}

__global__ __launch_bounds__(256) void finalize_kernel(
    float* __restrict__ out, const float* __restrict__ q, const float* __restrict__ scale)
{
    size_t i = (size_t)blockIdx.x * 256 + threadIdx.x;
    float4 v = ((const float4*)out)[i];
    float4 qq = ((const float4*)q)[i];
    float s = scale[(int)(i >> 8)];
    float4 o;
    o.x = v.x * s + qq.x;
    o.y = v.y * s + qq.y;
    o.z = v.z * s + qq.z;
    o.w = v.w * s + qq.w;
    ((float4*)out)[i] = o;
}

extern "C" void kernel_launch(void* const* d_in, const int* in_sizes, int n_in,
                              void* d_out, int out_size, void* d_ws, size_t ws_size,
                              hipStream_t stream) {
    const float* q      = (const float*)d_in[0];
    const float* cls1_w = (const float*)d_in[1];
    const float* cls1_b = (const float*)d_in[2];
    const float* cls3_w = (const float*)d_in[3];
    const float* cls3_b = (const float*)d_in[4];
    const float* exp_w1 = (const float*)d_in[5];
    const float* exp_b1 = (const float*)d_in[6];
    const float* exp_w2 = (const float*)d_in[7];
    const float* exp_b2 = (const float*)d_in[8];
    float* out = (float*)d_out;

    // ---- workspace layout (~60.5 MB) ----
    char* w = (char*)d_ws;
    float* psum   = (float*)w;              w += (size_t)NB * 8 * 4;
    float* gvalp  = (float*)w;              w += (size_t)NB * 4;
    float* scalep = (float*)w;              w += (size_t)NB * 4;
    int* top1     = (int*)w;                w += (size_t)NB * 4;
    int* brows    = (int*)w;                w += (size_t)NB * 4;
    int* ambig_rows = (int*)w;              w += (size_t)NB * 4;
    int* counts   = (int*)w;                w += 16 * 4;
    int* offsets  = (int*)w;                w += 16 * 4;
    int* bpos     = (int*)w;                w += 16 * 4;
    int* ambig_cnt = (int*)w;               w += 4 * 4;   // padded to 16B
    int* tm_e     = (int*)w;                w += NTILES * 4;
    int* tm_p     = (int*)w;                w += NTILES * 4;
    int* tm_end   = (int*)w;                w += NTILES * 4;
    unsigned short* qb   = (unsigned short*)w;  w += (size_t)NB * H * 2;
    unsigned short* w1b  = (unsigned short*)w;  w += (size_t)HH * H * 2;
    unsigned short* w3b  = (unsigned short*)w;  w += (size_t)NEXP * HH * 2;
    unsigned short* ew1b = (unsigned short*)w;  w += (size_t)NEXP * HH * H * 2;
    unsigned short* ew2b = (unsigned short*)w;  w += (size_t)NEXP * H * HH * 2;
    unsigned short* x1b  = (unsigned short*)w;  // 8.4 MB, ALIASED: x1 (gating) then h (experts)
    unsigned short* hbuf = x1b;              // safe: logits consumed before exp1 writes

    zero_kernel<<<1, 64, 0, stream>>>(counts, ambig_cnt);
    convert_plain<<<NB * H / 4 / 256, 256, 0, stream>>>(q, qb, NB * H / 4);
    convert_plain<<<HH * H / 4 / 256, 256, 0, stream>>>(cls1_w, w1b, HH * H / 4);
    convert_plain<<<NEXP * HH / 4 / 256 + 1, 256, 0, stream>>>(cls3_w, w3b, NEXP * HH / 4);
    convert_plain<<<NEXP * HH * H / 4 / 256, 256, 0, stream>>>(exp_w1, ew1b, NEXP * HH * H / 4);
    convert_plain<<<NEXP * H * HH / 4 / 256, 256, 0, stream>>>(exp_w2, ew2b, NEXP * H * HH / 4);

    g1_kernel<<<dim3(NB / 32, 4), 256, 0, stream>>>(qb, w1b, cls1_b, x1b);
    logits_kernel<<<NB / 32, 256, 0, stream>>>(x1b, w3b, cls3_b, top1, gvalp,
                                               ambig_rows, ambig_cnt);
    fixup_kernel<<<256, 256, 0, stream>>>(q, cls1_w, cls1_b, cls3_w, cls3_b,
                                          ambig_rows, ambig_cnt, top1, gvalp);
    count_kernel<<<NB / 256, 256, 0, stream>>>(top1, counts);
    offsets_kernel<<<1, 64, 0, stream>>>(counts, offsets, bpos, tm_e, tm_p, tm_end);
    scatter_kernel<<<NB / 256, 256, 0, stream>>>(top1, bpos, brows);

    exp1_kernel<<<dim3(NTILES, 4), 256, 0, stream>>>(qb, ew1b, exp_b1,
                                                     tm_e, tm_p, tm_end, brows, hbuf);
    exp2_kernel<<<dim3(NTILES, 8), 256, 0, stream>>>(hbuf, ew2b, exp_b2,
                                                     tm_e, tm_p, tm_end, brows, out, psum);
    scale_kernel<<<NB / 256, 256, 0, stream>>>(psum, gvalp, scalep);
    finalize_kernel<<<NB * H / 4 / 256, 256, 0, stream>>>(out, q, scalep);
}

// Round 4
// 578.433 us; speedup vs baseline: 1.3618x; 1.3618x over previous
//
#include <hip/hip_runtime.h>
#include <math.h>

#define NB 8192
#define H 1024
#define HH 512
#define NEXP 16
#define NTILES 272          // max sum of per-expert ceil(cnt/32)
#define AMBIG_THR 1e-3f     // ~50 sigma of split-bf16 logit error

// MFMA 16x16x32 bf16 fragments
typedef __attribute__((ext_vector_type(8))) short bfrag;
typedef __attribute__((ext_vector_type(4))) float f4;

__device__ __forceinline__ f4 MF(bfrag a, bfrag b, f4 c) {
    return __builtin_amdgcn_mfma_f32_16x16x32_bf16(a, b, c, 0, 0, 0);
}
__device__ __forceinline__ unsigned short f2bf(float f) {  // RNE fp32->bf16
    unsigned u = __float_as_uint(f);
    u += 0x7fff + ((u >> 16) & 1);
    return (unsigned short)(u >> 16);
}
__device__ __forceinline__ float bf2f(unsigned short h) {
    return __uint_as_float((unsigned)h << 16);
}

__global__ __launch_bounds__(64) void zero_kernel(int* counts, int* ambig_cnt) {
    if (threadIdx.x < NEXP) counts[threadIdx.x] = 0;
    if (threadIdx.x == 0) ambig_cnt[0] = 0;
}

// fused split-conversion: q (8192 blocks), w1 (512), w3 (8)
__global__ __launch_bounds__(256) void cvtA_kernel(
    const float* __restrict__ q, const float* __restrict__ w1, const float* __restrict__ w3,
    unsigned short* __restrict__ qhi, unsigned short* __restrict__ qlo,
    unsigned short* __restrict__ w1hi, unsigned short* __restrict__ w1lo,
    unsigned short* __restrict__ w3hi, unsigned short* __restrict__ w3lo)
{
    const int b = blockIdx.x, t = threadIdx.x;
    const float* src; unsigned short *hi, *lo; int i;
    if (b < 8192)      { src = q;  hi = qhi;  lo = qlo;  i = b * 256 + t; }
    else if (b < 8704) { src = w1; hi = w1hi; lo = w1lo; i = (b - 8192) * 256 + t; }
    else               { src = w3; hi = w3hi; lo = w3lo; i = (b - 8704) * 256 + t; }
    float4 v = ((const float4*)src)[i];
    ushort4 h, l;
    h.x = f2bf(v.x); l.x = f2bf(v.x - bf2f(h.x));
    h.y = f2bf(v.y); l.y = f2bf(v.y - bf2f(h.y));
    h.z = f2bf(v.z); l.z = f2bf(v.z - bf2f(h.z));
    h.w = f2bf(v.w); l.w = f2bf(v.w - bf2f(h.w));
    ((ushort4*)hi)[i] = h;
    ((ushort4*)lo)[i] = l;
}

// fused plain conversion: exp_w1 (8192 blocks), exp_w2 (8192 blocks)
__global__ __launch_bounds__(256) void cvtB_kernel(
    const float* __restrict__ ew1, const float* __restrict__ ew2,
    unsigned short* __restrict__ d1, unsigned short* __restrict__ d2)
{
    const int b = blockIdx.x, t = threadIdx.x;
    const float* src; unsigned short* dst; int i;
    if (b < 8192) { src = ew1; dst = d1; i = b * 256 + t; }
    else          { src = ew2; dst = d2; i = (b - 8192) * 256 + t; }
    float4 v = ((const float4*)src)[i];
    ushort4 h;
    h.x = f2bf(v.x); h.y = f2bf(v.y); h.z = f2bf(v.z); h.w = f2bf(v.w);
    ((ushort4*)dst)[i] = h;
}

// ---- gating GEMM1 (split 3-term): x1 = relu(q @ w1^T + b1), stored hi/lo ----
// grid (256, 4): 32 rows x 128 cols per block; wave owns 32 cols.
__global__ __launch_bounds__(256, 4) void g1_kernel(
    const unsigned short* __restrict__ qhi, const unsigned short* __restrict__ qlo,
    const unsigned short* __restrict__ w1hi, const unsigned short* __restrict__ w1lo,
    const float* __restrict__ b1,
    unsigned short* __restrict__ x1hi, unsigned short* __restrict__ x1lo)
{
    const int t = threadIdx.x, wave = t >> 6, lane = t & 63;
    const int quad = lane >> 4, l16 = lane & 15;
    const int row0 = blockIdx.x * 32;
    const int colbase = blockIdx.y * 128 + wave * 32;
    const f4 z4 = {0.f, 0.f, 0.f, 0.f};
    f4 acc[2][2] = {{z4, z4}, {z4, z4}};

    const size_t ar0 = (size_t)(row0 + l16) * H + quad * 8;
    const size_t ar1 = ar0 + (size_t)16 * H;
    const size_t br0 = (size_t)(colbase + l16) * H + quad * 8;
    const size_t br1 = br0 + (size_t)16 * H;
    for (int kk = 0; kk < H; kk += 32) {
        bfrag a0h = *(const bfrag*)(qhi + ar0 + kk);
        bfrag a0l = *(const bfrag*)(qlo + ar0 + kk);
        bfrag a1h = *(const bfrag*)(qhi + ar1 + kk);
        bfrag a1l = *(const bfrag*)(qlo + ar1 + kk);
        bfrag b0h = *(const bfrag*)(w1hi + br0 + kk);
        bfrag b0l = *(const bfrag*)(w1lo + br0 + kk);
        bfrag b1h = *(const bfrag*)(w1hi + br1 + kk);
        bfrag b1l = *(const bfrag*)(w1lo + br1 + kk);
        acc[0][0] = MF(a0l, b0h, MF(a0h, b0l, MF(a0h, b0h, acc[0][0])));
        acc[1][0] = MF(a1l, b0h, MF(a1h, b0l, MF(a1h, b0h, acc[1][0])));
        acc[0][1] = MF(a0l, b1h, MF(a0h, b1l, MF(a0h, b1h, acc[0][1])));
        acc[1][1] = MF(a1l, b1h, MF(a1h, b1l, MF(a1h, b1h, acc[1][1])));
    }
    #pragma unroll
    for (int cb = 0; cb < 2; ++cb) {
        int col = colbase + cb * 16 + l16;
        float bias = b1[col];
        #pragma unroll
        for (int rb = 0; rb < 2; ++rb)
            #pragma unroll
            for (int i = 0; i < 4; ++i) {
                int row = rb * 16 + quad * 4 + i;
                float v = fmaxf(acc[rb][cb][i] + bias, 0.f);
                unsigned short hh = f2bf(v);
                size_t idx = (size_t)(row0 + row) * HH + col;
                x1hi[idx] = hh;
                x1lo[idx] = f2bf(v - bf2f(hh));
            }
    }
}

// ---- logits (split 3-term) + argmax + gate + counts + ambiguity flag ----
__global__ __launch_bounds__(256) void logits_kernel(
    const unsigned short* __restrict__ x1hi, const unsigned short* __restrict__ x1lo,
    const unsigned short* __restrict__ w3hi, const unsigned short* __restrict__ w3lo,
    const float* __restrict__ b3,
    int* __restrict__ top1, float* __restrict__ gval, int* __restrict__ counts,
    int* __restrict__ ambig_rows, int* __restrict__ ambig_cnt)
{
    __shared__ float lgp[4][32][NEXP];
    const int t = threadIdx.x, wave = t >> 6, lane = t & 63;
    const int quad = lane >> 4, l16 = lane & 15;
    const int row0 = blockIdx.x * 32;
    const f4 z4 = {0.f, 0.f, 0.f, 0.f};

    f4 l0 = z4, l1 = z4;
    const size_t ar0 = (size_t)(row0 + l16) * HH + quad * 8;
    const size_t ar1 = ar0 + (size_t)16 * HH;
    const size_t br = (size_t)l16 * HH + quad * 8;
    #pragma unroll
    for (int ks = 0; ks < 4; ++ks) {
        int kk = wave * 128 + ks * 32;
        bfrag ah0 = *(const bfrag*)(x1hi + ar0 + kk);
        bfrag al0 = *(const bfrag*)(x1lo + ar0 + kk);
        bfrag ah1 = *(const bfrag*)(x1hi + ar1 + kk);
        bfrag al1 = *(const bfrag*)(x1lo + ar1 + kk);
        bfrag bh  = *(const bfrag*)(w3hi + br + kk);
        bfrag bl  = *(const bfrag*)(w3lo + br + kk);
        l0 = MF(al0, bh, MF(ah0, bl, MF(ah0, bh, l0)));
        l1 = MF(al1, bh, MF(ah1, bl, MF(ah1, bh, l1)));
    }
    #pragma unroll
    for (int i = 0; i < 4; ++i) {
        lgp[wave][quad * 4 + i][l16] = l0[i];
        lgp[wave][16 + quad * 4 + i][l16] = l1[i];
    }
    __syncthreads();

    if (t < 32) {
        float lg[NEXP];
        #pragma unroll
        for (int m = 0; m < NEXP; ++m)
            lg[m] = lgp[0][t][m] + lgp[1][t][m] + lgp[2][t][m] + lgp[3][t][m] + b3[m];
        float best = lg[0], second = -3.4e38f; int bi = 0;
        #pragma unroll
        for (int m = 1; m < NEXP; ++m) {
            float v = lg[m];
            if (v > best) { second = best; best = v; bi = m; }
            else if (v > second) second = v;
        }
        float se = 0.f;
        #pragma unroll
        for (int m = 0; m < NEXP; ++m) se += expf(lg[m] - best);
        int grow = row0 + t;
        top1[grow] = bi;
        gval[grow] = 1.f / se;
        atomicAdd(&counts[bi], 1);
        if (best - second < AMBIG_THR) {
            int pos = atomicAdd(ambig_cnt, 1);
            if (pos < NB) ambig_rows[pos] = grow;
        }
    }
}

// ---- exact fp32 recompute for ambiguous rows (expected ~2-5 rows) ----
// Coalesced: per column, 64 lanes cover contiguous chunks of one w1 row.
__global__ __launch_bounds__(256) void fixup_kernel(
    const float* __restrict__ q, const float* __restrict__ w1, const float* __restrict__ b1,
    const float* __restrict__ w3, const float* __restrict__ b3,
    const int* __restrict__ ambig_rows, const int* __restrict__ ambig_cnt,
    int* __restrict__ top1, float* __restrict__ gval, int* __restrict__ counts)
{
    __shared__ __align__(16) float qrow[H];
    __shared__ __align__(16) float x1[HH];
    __shared__ float lgs[NEXP];
    const int t = threadIdx.x, wv = t >> 6, ln = t & 63;
    int nn = *ambig_cnt; if (nn > NB) nn = NB;
    for (int ii = blockIdx.x; ii < nn; ii += gridDim.x) {
        int row = ambig_rows[ii];
        ((float4*)qrow)[t] = ((const float4*)(q + (size_t)row * H))[t];
        __syncthreads();
        // x1: wave wv handles col pairs (c, c+1), c = wv*2 + 8j
        for (int c = wv * 2; c < HH; c += 8) {
            const float4* w0 = (const float4*)(w1 + (size_t)c * H);
            const float4* w1r = (const float4*)(w1 + (size_t)(c + 1) * H);
            const float4* qv = (const float4*)qrow;
            float s0 = 0.f, s1 = 0.f;
            #pragma unroll
            for (int j = 0; j < 4; ++j) {
                float4 a = qv[j * 64 + ln];
                float4 b0 = w0[j * 64 + ln];
                float4 b1v = w1r[j * 64 + ln];
                s0 += a.x * b0.x + a.y * b0.y + a.z * b0.z + a.w * b0.w;
                s1 += a.x * b1v.x + a.y * b1v.y + a.z * b1v.z + a.w * b1v.w;
            }
            #pragma unroll
            for (int off = 32; off; off >>= 1) {
                s0 += __shfl_xor(s0, off, 64);
                s1 += __shfl_xor(s1, off, 64);
            }
            if (ln == 0) {
                x1[c]     = fmaxf(s0 + b1[c], 0.f);
                x1[c + 1] = fmaxf(s1 + b1[c + 1], 0.f);
            }
        }
        __syncthreads();
        // logits: wave wv handles experts wv, wv+4, wv+8, wv+12
        for (int m = wv; m < NEXP; m += 4) {
            const float4* wr = (const float4*)(w3 + (size_t)m * HH);
            const float4* xv = (const float4*)x1;
            float s = 0.f;
            #pragma unroll
            for (int j = 0; j < 2; ++j) {
                float4 a = xv[j * 64 + ln];
                float4 b = wr[j * 64 + ln];
                s += a.x * b.x + a.y * b.y + a.z * b.z + a.w * b.w;
            }
            #pragma unroll
            for (int off = 32; off; off >>= 1) s += __shfl_xor(s, off, 64);
            if (ln == 0) lgs[m] = s + b3[m];
        }
        __syncthreads();
        if (t == 0) {
            float best = lgs[0]; int bi = 0;
            #pragma unroll
            for (int m = 1; m < NEXP; ++m) if (lgs[m] > best) { best = lgs[m]; bi = m; }
            float se = 0.f;
            #pragma unroll
            for (int m = 0; m < NEXP; ++m) se += expf(lgs[m] - best);
            int old = top1[row];
            if (bi != old) {
                atomicSub(&counts[old], 1);
                atomicAdd(&counts[bi], 1);
                top1[row] = bi;
            }
            gval[row] = 1.f / se;
        }
        __syncthreads();
    }
}

// offsets + tile map (tile -> expert, start position, end position)
__global__ __launch_bounds__(64) void offsets_kernel(
    const int* __restrict__ counts, int* __restrict__ offsets, int* __restrict__ bpos,
    int* __restrict__ tm_e, int* __restrict__ tm_p, int* __restrict__ tm_end)
{
    if (threadIdx.x == 0) {
        int run = 0;
        for (int e = 0; e < NEXP; ++e) { offsets[e] = run; bpos[e] = run; run += counts[e]; }
        int tile = 0;
        for (int e = 0; e < NEXP; ++e) {
            int beg = offsets[e], end = beg + counts[e];
            for (int p = beg; p < end; p += 32) {
                tm_e[tile] = e; tm_p[tile] = p; tm_end[tile] = end; ++tile;
            }
        }
        for (; tile < NTILES; ++tile) tm_e[tile] = -1;
    }
}

__global__ __launch_bounds__(256) void scatter_kernel(
    const int* __restrict__ top1, int* __restrict__ bpos, int* __restrict__ brows)
{
    int b = blockIdx.x * 256 + threadIdx.x;
    int e = top1[b];
    int pos = atomicAdd(&bpos[e], 1);
    brows[pos] = b;
}

// ---- expert GEMM1: h[pos][512] = relu(q[row] @ w1[e]^T + b1[e]) ----
__global__ __launch_bounds__(256, 4) void exp1_kernel(
    const unsigned short* __restrict__ qb, const unsigned short* __restrict__ ew1b,
    const float* __restrict__ eb1,
    const int* __restrict__ tm_e, const int* __restrict__ tm_p, const int* __restrict__ tm_end,
    const int* __restrict__ brows, unsigned short* __restrict__ h)
{
    const int e = tm_e[blockIdx.x];
    if (e < 0) return;
    const int p0 = tm_p[blockIdx.x], end = tm_end[blockIdx.x];

    __shared__ int rrow[32];
    const int t = threadIdx.x, wave = t >> 6, lane = t & 63;
    const int quad = lane >> 4, l16 = lane & 15;
    if (t < 32) {
        int pos = p0 + t; if (pos >= end) pos = end - 1;
        rrow[t] = brows[pos];
    }
    __syncthreads();

    const int colbase = blockIdx.y * 128 + wave * 32;
    const unsigned short* w1p = ew1b + (size_t)e * HH * H;
    const f4 z4 = {0.f, 0.f, 0.f, 0.f};
    f4 acc[2][2] = {{z4, z4}, {z4, z4}};

    const size_t ar0 = (size_t)rrow[l16] * H + quad * 8;
    const size_t ar1 = (size_t)rrow[16 + l16] * H + quad * 8;
    const size_t br0 = (size_t)(colbase + l16) * H + quad * 8;
    #pragma unroll 2
    for (int kk = 0; kk < H; kk += 32) {
        bfrag a0 = *(const bfrag*)(qb + ar0 + kk);
        bfrag a1 = *(const bfrag*)(qb + ar1 + kk);
        bfrag bb0 = *(const bfrag*)(w1p + br0 + kk);
        bfrag bb1 = *(const bfrag*)(w1p + br0 + (size_t)16 * H + kk);
        acc[0][0] = MF(a0, bb0, acc[0][0]); acc[1][0] = MF(a1, bb0, acc[1][0]);
        acc[0][1] = MF(a0, bb1, acc[0][1]); acc[1][1] = MF(a1, bb1, acc[1][1]);
    }
    #pragma unroll
    for (int cb = 0; cb < 2; ++cb) {
        int col = colbase + cb * 16 + l16;
        float bias = eb1[e * HH + col];
        #pragma unroll
        for (int rb = 0; rb < 2; ++rb)
            #pragma unroll
            for (int i = 0; i < 4; ++i) {
                int row = rb * 16 + quad * 4 + i;
                if (p0 + row < end)
                    h[(size_t)(p0 + row) * HH + col] = f2bf(fmaxf(acc[rb][cb][i] + bias, 0.f));
            }
    }
}

// ---- expert GEMM2: v = h @ w2[e]^T + b2[e]; psum[row][chunk] = sum v^2 ----
__global__ __launch_bounds__(256, 4) void exp2_kernel(
    const unsigned short* __restrict__ h, const unsigned short* __restrict__ ew2b,
    const float* __restrict__ eb2,
    const int* __restrict__ tm_e, const int* __restrict__ tm_p, const int* __restrict__ tm_end,
    const int* __restrict__ brows,
    float* __restrict__ vout, float* __restrict__ psum)
{
    const int e = tm_e[blockIdx.x];
    if (e < 0) return;
    const int p0 = tm_p[blockIdx.x], end = tm_end[blockIdx.x];

    __shared__ int rrow[32];
    __shared__ float rqp[4][32];
    const int t = threadIdx.x, wave = t >> 6, lane = t & 63;
    const int quad = lane >> 4, l16 = lane & 15;
    if (t < 32) {
        int pos = p0 + t; if (pos >= end) pos = end - 1;
        rrow[t] = brows[pos];
    }
    __syncthreads();

    const int colbase = blockIdx.y * 128 + wave * 32;
    const unsigned short* w2p = ew2b + (size_t)e * H * HH;
    const f4 z4 = {0.f, 0.f, 0.f, 0.f};
    f4 acc[2][2] = {{z4, z4}, {z4, z4}};

    int hp0 = p0 + l16;      if (hp0 >= end) hp0 = end - 1;
    int hp1 = p0 + 16 + l16; if (hp1 >= end) hp1 = end - 1;
    const size_t ar0 = (size_t)hp0 * HH + quad * 8;
    const size_t ar1 = (size_t)hp1 * HH + quad * 8;
    const size_t br0 = (size_t)(colbase + l16) * HH + quad * 8;
    #pragma unroll 2
    for (int kk = 0; kk < HH; kk += 32) {
        bfrag a0 = *(const bfrag*)(h + ar0 + kk);
        bfrag a1 = *(const bfrag*)(h + ar1 + kk);
        bfrag bb0 = *(const bfrag*)(w2p + br0 + kk);
        bfrag bb1 = *(const bfrag*)(w2p + br0 + (size_t)16 * HH + kk);
        acc[0][0] = MF(a0, bb0, acc[0][0]); acc[1][0] = MF(a1, bb0, acc[1][0]);
        acc[0][1] = MF(a0, bb1, acc[0][1]); acc[1][1] = MF(a1, bb1, acc[1][1]);
    }

    float rs0[4] = {0.f, 0.f, 0.f, 0.f}, rs1[4] = {0.f, 0.f, 0.f, 0.f};
    #pragma unroll
    for (int cb = 0; cb < 2; ++cb) {
        int col = colbase + cb * 16 + l16;
        float bias = eb2[e * H + col];
        #pragma unroll
        for (int i = 0; i < 4; ++i) {
            float v0 = acc[0][cb][i] + bias;
            float v1 = acc[1][cb][i] + bias;
            int r0 = quad * 4 + i, r1 = 16 + quad * 4 + i;
            vout[(size_t)rrow[r0] * H + col] = v0;
            vout[(size_t)rrow[r1] * H + col] = v1;
            rs0[i] += v0 * v0;
            rs1[i] += v1 * v1;
        }
    }
    #pragma unroll
    for (int i = 0; i < 4; ++i) {
        float s0 = rs0[i], s1 = rs1[i];
        #pragma unroll
        for (int off = 8; off; off >>= 1) {
            s0 += __shfl_xor(s0, off, 16);
            s1 += __shfl_xor(s1, off, 16);
        }
        if (l16 == 0) {
            rqp[wave][quad * 4 + i] = s0;
            rqp[wave][16 + quad * 4 + i] = s1;
        }
    }
    __syncthreads();
    if (t < 32)
        psum[(size_t)rrow[t] * 8 + blockIdx.y] = rqp[0][t] + rqp[1][t] + rqp[2][t] + rqp[3][t];
}

__global__ __launch_bounds__(256) void scale_kernel(
    const float* __restrict__ psum, const float* __restrict__ gval, float* __restrict__ scale)
{
    int r = blockIdx.x * 256 + threadIdx.x;
    float s = 0.f;
    #pragma unroll
    for (int j = 0; j < 8; ++j) s += psum[(size_t)r * 8 + j];
    float n = sqrtf(s);
    float g = gval[r];
    scale[r] = g / fmaxf(g * n, 1e-6f);
}

__global__ __launch_bounds__(256) void finalize_kernel(
    float* __restrict__ out, const float* __restrict__ q, const float* __restrict__ scale)
{
    size_t i = (size_t)blockIdx.x * 256 + threadIdx.x;
    float4 v = ((const float4*)out)[i];
    float4 qq = ((const float4*)q)[i];
    float s = scale[(int)(i >> 8)];
    float4 o;
    o.x = v.x * s + qq.x;
    o.y = v.y * s + qq.y;
    o.z = v.z * s + qq.z;
    o.w = v.w * s + qq.w;
    ((float4*)out)[i] = o;
}

extern "C" void kernel_launch(void* const* d_in, const int* in_sizes, int n_in,
                              void* d_out, int out_size, void* d_ws, size_t ws_size,
                              hipStream_t stream) {
    const float* q      = (const float*)d_in[0];
    const float* cls1_w = (const float*)d_in[1];
    const float* cls1_b = (const float*)d_in[2];
    const float* cls3_w = (const float*)d_in[3];
    const float* cls3_b = (const float*)d_in[4];
    const float* exp_w1 = (const float*)d_in[5];
    const float* exp_b1 = (const float*)d_in[6];
    const float* exp_w2 = (const float*)d_in[7];
    const float* exp_b2 = (const float*)d_in[8];
    float* out = (float*)d_out;

    // ---- workspace layout (~61.5 MB), with lifetime-based aliasing ----
    char* w = (char*)d_ws;
    float* psum   = (float*)w;              w += (size_t)NB * 8 * 4;
    float* gvalp  = (float*)w;              w += (size_t)NB * 4;
    float* scalep = (float*)w;              w += (size_t)NB * 4;
    int* top1     = (int*)w;                w += (size_t)NB * 4;
    int* brows    = (int*)w;                w += (size_t)NB * 4;
    int* ambig_rows = (int*)w;              w += (size_t)NB * 4;
    int* counts   = (int*)w;                w += 16 * 4;
    int* offsets  = (int*)w;                w += 16 * 4;
    int* bpos     = (int*)w;                w += 16 * 4;
    int* ambig_cnt = (int*)w;               w += 4 * 4;
    int* tm_e     = (int*)w;                w += NTILES * 4;
    int* tm_p     = (int*)w;                w += NTILES * 4;
    int* tm_end   = (int*)w;                w += NTILES * 4;
    w = (char*)(((size_t)w + 15) & ~(size_t)15);
    unsigned short* qhi  = (unsigned short*)w;  w += (size_t)NB * H * 2;       // lives whole pipeline
    unsigned short* qlo  = (unsigned short*)w;  w += (size_t)NB * H * 2;       // dead after g1 -> ew2b
    unsigned short* x1hi = (unsigned short*)w;                                  // dead after logits
    unsigned short* x1lo = x1hi + (size_t)NB * HH;  w += (size_t)NB * HH * 2 * 2;  // -> ew1b (both halves)
    unsigned short* hbuf = (unsigned short*)w;  w += (size_t)NB * HH * 2;
    unsigned short* w1hi = (unsigned short*)w;  w += (size_t)HH * H * 2;
    unsigned short* w1lo = (unsigned short*)w;  w += (size_t)HH * H * 2;
    unsigned short* w3hi = (unsigned short*)w;  w += (size_t)NEXP * HH * 2;
    unsigned short* w3lo = (unsigned short*)w;  w += (size_t)NEXP * HH * 2;
    unsigned short* ew1b = x1hi;   // 16.78 MB region, reused after logits
    unsigned short* ew2b = qlo;    // 16.78 MB region, reused after g1

    zero_kernel<<<1, 64, 0, stream>>>(counts, ambig_cnt);
    cvtA_kernel<<<8712, 256, 0, stream>>>(q, cls1_w, cls3_w, qhi, qlo, w1hi, w1lo, w3hi, w3lo);
    g1_kernel<<<dim3(NB / 32, 4), 256, 0, stream>>>(qhi, qlo, w1hi, w1lo, cls1_b, x1hi, x1lo);
    logits_kernel<<<NB / 32, 256, 0, stream>>>(x1hi, x1lo, w3hi, w3lo, cls3_b,
                                               top1, gvalp, counts, ambig_rows, ambig_cnt);
    fixup_kernel<<<256, 256, 0, stream>>>(q, cls1_w, cls1_b, cls3_w, cls3_b,
                                          ambig_rows, ambig_cnt, top1, gvalp, counts);
    // conversions into the now-dead x1 / qlo regions (stream is serial: position is free)
    cvtB_kernel<<<16384, 256, 0, stream>>>(exp_w1, exp_w2, ew1b, ew2b);
    offsets_kernel<<<1, 64, 0, stream>>>(counts, offsets, bpos, tm_e, tm_p, tm_end);
    scatter_kernel<<<NB / 256, 256, 0, stream>>>(top1, bpos, brows);
    exp1_kernel<<<dim3(NTILES, 4), 256, 0, stream>>>(qhi, ew1b, exp_b1,
                                                     tm_e, tm_p, tm_end, brows, hbuf);
    exp2_kernel<<<dim3(NTILES, 8), 256, 0, stream>>>(hbuf, ew2b, exp_b2,
                                                     tm_e, tm_p, tm_end, brows, out, psum);
    scale_kernel<<<NB / 256, 256, 0, stream>>>(psum, gvalp, scalep);
    finalize_kernel<<<NB * H / 4 / 256, 256, 0, stream>>>(out, q, scalep);
}

// Round 5
// 512.004 us; speedup vs baseline: 1.5385x; 1.1297x over previous
//
#include <hip/hip_runtime.h>
#include <math.h>

#define NB 8192
#define H 1024
#define HH 512
#define NEXP 16
#define NTILES 272          // max sum of per-expert ceil(cnt/32)
#define AMBIG_THR 1e-3f     // ~50 sigma of split-bf16 logit error

// MFMA 16x16x32 bf16 fragments
typedef __attribute__((ext_vector_type(8))) short bfrag;
typedef __attribute__((ext_vector_type(4))) float f4;

__device__ __forceinline__ f4 MF(bfrag a, bfrag b, f4 c) {
    return __builtin_amdgcn_mfma_f32_16x16x32_bf16(a, b, c, 0, 0, 0);
}
__device__ __forceinline__ unsigned short f2bf(float f) {  // RNE fp32->bf16
    unsigned u = __float_as_uint(f);
    u += 0x7fff + ((u >> 16) & 1);
    return (unsigned short)(u >> 16);
}
__device__ __forceinline__ float bf2f(unsigned short h) {
    return __uint_as_float((unsigned)h << 16);
}

// fused split-conversion: q (8192 blocks), w1 (512), w3 (8); block 0 zeroes counters
__global__ __launch_bounds__(256) void cvtA_kernel(
    const float* __restrict__ q, const float* __restrict__ w1, const float* __restrict__ w3,
    unsigned short* __restrict__ qhi, unsigned short* __restrict__ qlo,
    unsigned short* __restrict__ w1hi, unsigned short* __restrict__ w1lo,
    unsigned short* __restrict__ w3hi, unsigned short* __restrict__ w3lo,
    int* __restrict__ counts, int* __restrict__ ambig_cnt)
{
    const int b = blockIdx.x, t = threadIdx.x;
    if (b == 0) {
        if (t < NEXP) counts[t] = 0;
        if (t == NEXP) ambig_cnt[0] = 0;
    }
    const float* src; unsigned short *hi, *lo; int i;
    if (b < 8192)      { src = q;  hi = qhi;  lo = qlo;  i = b * 256 + t; }
    else if (b < 8704) { src = w1; hi = w1hi; lo = w1lo; i = (b - 8192) * 256 + t; }
    else               { src = w3; hi = w3hi; lo = w3lo; i = (b - 8704) * 256 + t; }
    float4 v = ((const float4*)src)[i];
    ushort4 h, l;
    h.x = f2bf(v.x); l.x = f2bf(v.x - bf2f(h.x));
    h.y = f2bf(v.y); l.y = f2bf(v.y - bf2f(h.y));
    h.z = f2bf(v.z); l.z = f2bf(v.z - bf2f(h.z));
    h.w = f2bf(v.w); l.w = f2bf(v.w - bf2f(h.w));
    ((ushort4*)hi)[i] = h;
    ((ushort4*)lo)[i] = l;
}

// fused plain conversion: exp_w1 (8192 blocks), exp_w2 (8192 blocks)
__global__ __launch_bounds__(256) void cvtB_kernel(
    const float* __restrict__ ew1, const float* __restrict__ ew2,
    unsigned short* __restrict__ d1, unsigned short* __restrict__ d2)
{
    const int b = blockIdx.x, t = threadIdx.x;
    const float* src; unsigned short* dst; int i;
    if (b < 8192) { src = ew1; dst = d1; i = b * 256 + t; }
    else          { src = ew2; dst = d2; i = (b - 8192) * 256 + t; }
    float4 v = ((const float4*)src)[i];
    ushort4 h;
    h.x = f2bf(v.x); h.y = f2bf(v.y); h.z = f2bf(v.z); h.w = f2bf(v.w);
    ((ushort4*)dst)[i] = h;
}

// ---- gating GEMM1 (split 3-term): x1 = relu(q @ w1^T + b1), stored hi/lo ----
// single-wave blocks; wave tile = 32 rows x 64 cols; grid (256, 8).
__global__ __launch_bounds__(64) void g1_kernel(
    const unsigned short* __restrict__ qhi, const unsigned short* __restrict__ qlo,
    const unsigned short* __restrict__ w1hi, const unsigned short* __restrict__ w1lo,
    const float* __restrict__ b1,
    unsigned short* __restrict__ x1hi, unsigned short* __restrict__ x1lo)
{
    const int lane = threadIdx.x & 63, quad = lane >> 4, l16 = lane & 15;
    const int row0 = blockIdx.x * 32;
    const int c0 = blockIdx.y * 64;
    const f4 z4 = {0.f, 0.f, 0.f, 0.f};
    f4 acc[2][4] = {{z4, z4, z4, z4}, {z4, z4, z4, z4}};

    const size_t ar0 = (size_t)(row0 + l16) * H + quad * 8;
    const size_t ar1 = ar0 + (size_t)16 * H;
    size_t br[4];
    #pragma unroll
    for (int cb = 0; cb < 4; ++cb) br[cb] = (size_t)(c0 + cb * 16 + l16) * H + quad * 8;

    bfrag a0h = *(const bfrag*)(qhi + ar0);
    bfrag a0l = *(const bfrag*)(qlo + ar0);
    bfrag a1h = *(const bfrag*)(qhi + ar1);
    bfrag a1l = *(const bfrag*)(qlo + ar1);
    bfrag bh[4], bl[4];
    #pragma unroll
    for (int cb = 0; cb < 4; ++cb) {
        bh[cb] = *(const bfrag*)(w1hi + br[cb]);
        bl[cb] = *(const bfrag*)(w1lo + br[cb]);
    }
    #pragma unroll 2
    for (int kk = 32; kk <= H - 32; kk += 32) {
        bfrag na0h = *(const bfrag*)(qhi + ar0 + kk);
        bfrag na0l = *(const bfrag*)(qlo + ar0 + kk);
        bfrag na1h = *(const bfrag*)(qhi + ar1 + kk);
        bfrag na1l = *(const bfrag*)(qlo + ar1 + kk);
        bfrag nbh[4], nbl[4];
        #pragma unroll
        for (int cb = 0; cb < 4; ++cb) {
            nbh[cb] = *(const bfrag*)(w1hi + br[cb] + kk);
            nbl[cb] = *(const bfrag*)(w1lo + br[cb] + kk);
        }
        #pragma unroll
        for (int cb = 0; cb < 4; ++cb) {
            acc[0][cb] = MF(a0l, bh[cb], MF(a0h, bl[cb], MF(a0h, bh[cb], acc[0][cb])));
            acc[1][cb] = MF(a1l, bh[cb], MF(a1h, bl[cb], MF(a1h, bh[cb], acc[1][cb])));
        }
        a0h = na0h; a0l = na0l; a1h = na1h; a1l = na1l;
        #pragma unroll
        for (int cb = 0; cb < 4; ++cb) { bh[cb] = nbh[cb]; bl[cb] = nbl[cb]; }
    }
    #pragma unroll
    for (int cb = 0; cb < 4; ++cb) {
        acc[0][cb] = MF(a0l, bh[cb], MF(a0h, bl[cb], MF(a0h, bh[cb], acc[0][cb])));
        acc[1][cb] = MF(a1l, bh[cb], MF(a1h, bl[cb], MF(a1h, bh[cb], acc[1][cb])));
    }

    #pragma unroll
    for (int cb = 0; cb < 4; ++cb) {
        int col = c0 + cb * 16 + l16;
        float bias = b1[col];
        #pragma unroll
        for (int rb = 0; rb < 2; ++rb)
            #pragma unroll
            for (int i = 0; i < 4; ++i) {
                int row = rb * 16 + quad * 4 + i;
                float v = fmaxf(acc[rb][cb][i] + bias, 0.f);
                unsigned short hh = f2bf(v);
                size_t idx = (size_t)(row0 + row) * HH + col;
                x1hi[idx] = hh;
                x1lo[idx] = f2bf(v - bf2f(hh));
            }
    }
}

// ---- logits (split 3-term) + argmax + gate + counts + ambiguity flag ----
__global__ __launch_bounds__(256) void logits_kernel(
    const unsigned short* __restrict__ x1hi, const unsigned short* __restrict__ x1lo,
    const unsigned short* __restrict__ w3hi, const unsigned short* __restrict__ w3lo,
    const float* __restrict__ b3,
    int* __restrict__ top1, float* __restrict__ gval, int* __restrict__ counts,
    int* __restrict__ ambig_rows, int* __restrict__ ambig_cnt)
{
    __shared__ float lgp[4][32][NEXP];
    const int t = threadIdx.x, wave = t >> 6, lane = t & 63;
    const int quad = lane >> 4, l16 = lane & 15;
    const int row0 = blockIdx.x * 32;
    const f4 z4 = {0.f, 0.f, 0.f, 0.f};

    f4 l0 = z4, l1 = z4;
    const size_t ar0 = (size_t)(row0 + l16) * HH + quad * 8;
    const size_t ar1 = ar0 + (size_t)16 * HH;
    const size_t br = (size_t)l16 * HH + quad * 8;
    #pragma unroll
    for (int ks = 0; ks < 4; ++ks) {
        int kk = wave * 128 + ks * 32;
        bfrag ah0 = *(const bfrag*)(x1hi + ar0 + kk);
        bfrag al0 = *(const bfrag*)(x1lo + ar0 + kk);
        bfrag ah1 = *(const bfrag*)(x1hi + ar1 + kk);
        bfrag al1 = *(const bfrag*)(x1lo + ar1 + kk);
        bfrag bh  = *(const bfrag*)(w3hi + br + kk);
        bfrag bl  = *(const bfrag*)(w3lo + br + kk);
        l0 = MF(al0, bh, MF(ah0, bl, MF(ah0, bh, l0)));
        l1 = MF(al1, bh, MF(ah1, bl, MF(ah1, bh, l1)));
    }
    #pragma unroll
    for (int i = 0; i < 4; ++i) {
        lgp[wave][quad * 4 + i][l16] = l0[i];
        lgp[wave][16 + quad * 4 + i][l16] = l1[i];
    }
    __syncthreads();

    if (t < 32) {
        float lg[NEXP];
        #pragma unroll
        for (int m = 0; m < NEXP; ++m)
            lg[m] = lgp[0][t][m] + lgp[1][t][m] + lgp[2][t][m] + lgp[3][t][m] + b3[m];
        float best = lg[0], second = -3.4e38f; int bi = 0;
        #pragma unroll
        for (int m = 1; m < NEXP; ++m) {
            float v = lg[m];
            if (v > best) { second = best; best = v; bi = m; }
            else if (v > second) second = v;
        }
        float se = 0.f;
        #pragma unroll
        for (int m = 0; m < NEXP; ++m) se += expf(lg[m] - best);
        int grow = row0 + t;
        top1[grow] = bi;
        gval[grow] = 1.f / se;
        atomicAdd(&counts[bi], 1);
        if (best - second < AMBIG_THR) {
            int pos = atomicAdd(ambig_cnt, 1);
            if (pos < NB) ambig_rows[pos] = grow;
        }
    }
}

// ---- exact fp32 recompute for ambiguous rows (expected ~2-5 rows) ----
__global__ __launch_bounds__(256) void fixup_kernel(
    const float* __restrict__ q, const float* __restrict__ w1, const float* __restrict__ b1,
    const float* __restrict__ w3, const float* __restrict__ b3,
    const int* __restrict__ ambig_rows, const int* __restrict__ ambig_cnt,
    int* __restrict__ top1, float* __restrict__ gval, int* __restrict__ counts)
{
    __shared__ __align__(16) float qrow[H];
    __shared__ __align__(16) float x1[HH];
    __shared__ float lgs[NEXP];
    const int t = threadIdx.x, wv = t >> 6, ln = t & 63;
    int nn = *ambig_cnt; if (nn > NB) nn = NB;
    for (int ii = blockIdx.x; ii < nn; ii += gridDim.x) {
        int row = ambig_rows[ii];
        ((float4*)qrow)[t] = ((const float4*)(q + (size_t)row * H))[t];
        __syncthreads();
        for (int c = wv * 2; c < HH; c += 8) {
            const float4* w0 = (const float4*)(w1 + (size_t)c * H);
            const float4* w1r = (const float4*)(w1 + (size_t)(c + 1) * H);
            const float4* qv = (const float4*)qrow;
            float s0 = 0.f, s1 = 0.f;
            #pragma unroll
            for (int j = 0; j < 4; ++j) {
                float4 a = qv[j * 64 + ln];
                float4 b0 = w0[j * 64 + ln];
                float4 b1v = w1r[j * 64 + ln];
                s0 += a.x * b0.x + a.y * b0.y + a.z * b0.z + a.w * b0.w;
                s1 += a.x * b1v.x + a.y * b1v.y + a.z * b1v.z + a.w * b1v.w;
            }
            #pragma unroll
            for (int off = 32; off; off >>= 1) {
                s0 += __shfl_xor(s0, off, 64);
                s1 += __shfl_xor(s1, off, 64);
            }
            if (ln == 0) {
                x1[c]     = fmaxf(s0 + b1[c], 0.f);
                x1[c + 1] = fmaxf(s1 + b1[c + 1], 0.f);
            }
        }
        __syncthreads();
        for (int m = wv; m < NEXP; m += 4) {
            const float4* wr = (const float4*)(w3 + (size_t)m * HH);
            const float4* xv = (const float4*)x1;
            float s = 0.f;
            #pragma unroll
            for (int j = 0; j < 2; ++j) {
                float4 a = xv[j * 64 + ln];
                float4 b = wr[j * 64 + ln];
                s += a.x * b.x + a.y * b.y + a.z * b.z + a.w * b.w;
            }
            #pragma unroll
            for (int off = 32; off; off >>= 1) s += __shfl_xor(s, off, 64);
            if (ln == 0) lgs[m] = s + b3[m];
        }
        __syncthreads();
        if (t == 0) {
            float best = lgs[0]; int bi = 0;
            #pragma unroll
            for (int m = 1; m < NEXP; ++m) if (lgs[m] > best) { best = lgs[m]; bi = m; }
            float se = 0.f;
            #pragma unroll
            for (int m = 0; m < NEXP; ++m) se += expf(lgs[m] - best);
            int old = top1[row];
            if (bi != old) {
                atomicSub(&counts[old], 1);
                atomicAdd(&counts[bi], 1);
                top1[row] = bi;
            }
            gval[row] = 1.f / se;
        }
        __syncthreads();
    }
}

// offsets + tile map
__global__ __launch_bounds__(64) void offsets_kernel(
    const int* __restrict__ counts, int* __restrict__ offsets, int* __restrict__ bpos,
    int* __restrict__ tm_e, int* __restrict__ tm_p, int* __restrict__ tm_end)
{
    if (threadIdx.x == 0) {
        int run = 0;
        for (int e = 0; e < NEXP; ++e) { offsets[e] = run; bpos[e] = run; run += counts[e]; }
        int tile = 0;
        for (int e = 0; e < NEXP; ++e) {
            int beg = offsets[e], end = beg + counts[e];
            for (int p = beg; p < end; p += 32) {
                tm_e[tile] = e; tm_p[tile] = p; tm_end[tile] = end; ++tile;
            }
        }
        for (; tile < NTILES; ++tile) tm_e[tile] = -1;
    }
}

__global__ __launch_bounds__(256) void scatter_kernel(
    const int* __restrict__ top1, int* __restrict__ bpos, int* __restrict__ brows)
{
    int b = blockIdx.x * 256 + threadIdx.x;
    int e = top1[b];
    int pos = atomicAdd(&bpos[e], 1);
    brows[pos] = b;
}

// ---- expert GEMM1: h[pos][512] = relu(q[row] @ w1[e]^T + b1[e]) ----
// single-wave; wave tile 32 x 64; grid (NTILES, 8).
__global__ __launch_bounds__(64) void exp1_kernel(
    const unsigned short* __restrict__ qb, const unsigned short* __restrict__ ew1b,
    const float* __restrict__ eb1,
    const int* __restrict__ tm_e, const int* __restrict__ tm_p, const int* __restrict__ tm_end,
    const int* __restrict__ brows, unsigned short* __restrict__ h)
{
    const int e = tm_e[blockIdx.x];
    if (e < 0) return;
    const int p0 = tm_p[blockIdx.x], end = tm_end[blockIdx.x];
    const int lane = threadIdx.x & 63, quad = lane >> 4, l16 = lane & 15;

    int pa = p0 + l16;      if (pa >= end) pa = end - 1;
    int pb = p0 + 16 + l16; if (pb >= end) pb = end - 1;
    const int r0 = brows[pa], r1 = brows[pb];

    const int c0 = blockIdx.y * 64;
    const unsigned short* w1p = ew1b + (size_t)e * HH * H;
    const f4 z4 = {0.f, 0.f, 0.f, 0.f};
    f4 acc[2][4] = {{z4, z4, z4, z4}, {z4, z4, z4, z4}};

    const size_t ar0 = (size_t)r0 * H + quad * 8;
    const size_t ar1 = (size_t)r1 * H + quad * 8;
    size_t br[4];
    #pragma unroll
    for (int cb = 0; cb < 4; ++cb) br[cb] = (size_t)(c0 + cb * 16 + l16) * H + quad * 8;

    bfrag a0 = *(const bfrag*)(qb + ar0);
    bfrag a1 = *(const bfrag*)(qb + ar1);
    bfrag bb[4];
    #pragma unroll
    for (int cb = 0; cb < 4; ++cb) bb[cb] = *(const bfrag*)(w1p + br[cb]);
    #pragma unroll 2
    for (int kk = 32; kk <= H - 32; kk += 32) {
        bfrag na0 = *(const bfrag*)(qb + ar0 + kk);
        bfrag na1 = *(const bfrag*)(qb + ar1 + kk);
        bfrag nbb[4];
        #pragma unroll
        for (int cb = 0; cb < 4; ++cb) nbb[cb] = *(const bfrag*)(w1p + br[cb] + kk);
        #pragma unroll
        for (int cb = 0; cb < 4; ++cb) {
            acc[0][cb] = MF(a0, bb[cb], acc[0][cb]);
            acc[1][cb] = MF(a1, bb[cb], acc[1][cb]);
        }
        a0 = na0; a1 = na1;
        #pragma unroll
        for (int cb = 0; cb < 4; ++cb) bb[cb] = nbb[cb];
    }
    #pragma unroll
    for (int cb = 0; cb < 4; ++cb) {
        acc[0][cb] = MF(a0, bb[cb], acc[0][cb]);
        acc[1][cb] = MF(a1, bb[cb], acc[1][cb]);
    }

    #pragma unroll
    for (int cb = 0; cb < 4; ++cb) {
        int col = c0 + cb * 16 + l16;
        float bias = eb1[e * HH + col];
        #pragma unroll
        for (int rb = 0; rb < 2; ++rb)
            #pragma unroll
            for (int i = 0; i < 4; ++i) {
                int row = rb * 16 + quad * 4 + i;
                if (p0 + row < end)
                    h[(size_t)(p0 + row) * HH + col] = f2bf(fmaxf(acc[rb][cb][i] + bias, 0.f));
            }
    }
}

// ---- expert GEMM2: v = h @ w2[e]^T + b2[e]; psum[row][cg] = partial sum v^2 ----
// single-wave; wave tile 32 x 64; grid (NTILES, 16).
__global__ __launch_bounds__(64) void exp2_kernel(
    const unsigned short* __restrict__ h, const unsigned short* __restrict__ ew2b,
    const float* __restrict__ eb2,
    const int* __restrict__ tm_e, const int* __restrict__ tm_p, const int* __restrict__ tm_end,
    const int* __restrict__ brows,
    float* __restrict__ vout, float* __restrict__ psum)
{
    const int e = tm_e[blockIdx.x];
    if (e < 0) return;
    const int p0 = tm_p[blockIdx.x], end = tm_end[blockIdx.x];
    const int lane = threadIdx.x & 63, quad = lane >> 4, l16 = lane & 15;
    const int cg = blockIdx.y;

    int pa = p0 + l16;      if (pa >= end) pa = end - 1;
    int pb = p0 + 16 + l16; if (pb >= end) pb = end - 1;

    const int c0 = cg * 64;
    const unsigned short* w2p = ew2b + (size_t)e * H * HH;
    const f4 z4 = {0.f, 0.f, 0.f, 0.f};
    f4 acc[2][4] = {{z4, z4, z4, z4}, {z4, z4, z4, z4}};

    const size_t ar0 = (size_t)pa * HH + quad * 8;
    const size_t ar1 = (size_t)pb * HH + quad * 8;
    size_t br[4];
    #pragma unroll
    for (int cb = 0; cb < 4; ++cb) br[cb] = (size_t)(c0 + cb * 16 + l16) * HH + quad * 8;

    bfrag a0 = *(const bfrag*)(h + ar0);
    bfrag a1 = *(const bfrag*)(h + ar1);
    bfrag bb[4];
    #pragma unroll
    for (int cb = 0; cb < 4; ++cb) bb[cb] = *(const bfrag*)(w2p + br[cb]);
    #pragma unroll 2
    for (int kk = 32; kk <= HH - 32; kk += 32) {
        bfrag na0 = *(const bfrag*)(h + ar0 + kk);
        bfrag na1 = *(const bfrag*)(h + ar1 + kk);
        bfrag nbb[4];
        #pragma unroll
        for (int cb = 0; cb < 4; ++cb) nbb[cb] = *(const bfrag*)(w2p + br[cb] + kk);
        #pragma unroll
        for (int cb = 0; cb < 4; ++cb) {
            acc[0][cb] = MF(a0, bb[cb], acc[0][cb]);
            acc[1][cb] = MF(a1, bb[cb], acc[1][cb]);
        }
        a0 = na0; a1 = na1;
        #pragma unroll
        for (int cb = 0; cb < 4; ++cb) bb[cb] = nbb[cb];
    }
    #pragma unroll
    for (int cb = 0; cb < 4; ++cb) {
        acc[0][cb] = MF(a0, bb[cb], acc[0][cb]);
        acc[1][cb] = MF(a1, bb[cb], acc[1][cb]);
    }

    // bias + v-write + per-row sum(v^2)
    float rs0[4] = {0.f, 0.f, 0.f, 0.f}, rs1[4] = {0.f, 0.f, 0.f, 0.f};
    #pragma unroll
    for (int i = 0; i < 4; ++i) {
        int row0i = quad * 4 + i, row1i = 16 + quad * 4 + i;
        int g0 = p0 + row0i; if (g0 >= end) g0 = end - 1;
        int g1 = p0 + row1i; if (g1 >= end) g1 = end - 1;
        int gr0 = brows[g0], gr1 = brows[g1];
        #pragma unroll
        for (int cb = 0; cb < 4; ++cb) {
            int col = c0 + cb * 16 + l16;
            float bias = eb2[e * H + col];
            float v0 = acc[0][cb][i] + bias;
            float v1 = acc[1][cb][i] + bias;
            vout[(size_t)gr0 * H + col] = v0;
            vout[(size_t)gr1 * H + col] = v1;
            rs0[i] += v0 * v0;
            rs1[i] += v1 * v1;
        }
    }
    #pragma unroll
    for (int i = 0; i < 4; ++i) {
        float s0 = rs0[i], s1 = rs1[i];
        #pragma unroll
        for (int off = 8; off; off >>= 1) {
            s0 += __shfl_xor(s0, off, 16);
            s1 += __shfl_xor(s1, off, 16);
        }
        if (l16 == 0) {
            int g0 = p0 + quad * 4 + i;      if (g0 >= end) g0 = end - 1;
            int g1 = p0 + 16 + quad * 4 + i; if (g1 >= end) g1 = end - 1;
            psum[(size_t)brows[g0] * 16 + cg] = s0;
            psum[(size_t)brows[g1] * 16 + cg] = s1;
        }
    }
}

// out = v * scale + q ; scale computed inline from psum (one block per row)
__global__ __launch_bounds__(256) void finalize_kernel(
    float* __restrict__ out, const float* __restrict__ q,
    const float* __restrict__ psum, const float* __restrict__ gval)
{
    const int row = blockIdx.x, t = threadIdx.x;
    float s = 0.f;
    #pragma unroll
    for (int j = 0; j < 16; ++j) s += psum[(size_t)row * 16 + j];
    float g = gval[row];
    float sc = g / fmaxf(g * sqrtf(s), 1e-6f);
    size_t i = (size_t)row * 256 + t;
    float4 v = ((const float4*)out)[i];
    float4 qq = ((const float4*)q)[i];
    float4 o;
    o.x = v.x * sc + qq.x;
    o.y = v.y * sc + qq.y;
    o.z = v.z * sc + qq.z;
    o.w = v.w * sc + qq.w;
    ((float4*)out)[i] = o;
}

extern "C" void kernel_launch(void* const* d_in, const int* in_sizes, int n_in,
                              void* d_out, int out_size, void* d_ws, size_t ws_size,
                              hipStream_t stream) {
    const float* q      = (const float*)d_in[0];
    const float* cls1_w = (const float*)d_in[1];
    const float* cls1_b = (const float*)d_in[2];
    const float* cls3_w = (const float*)d_in[3];
    const float* cls3_b = (const float*)d_in[4];
    const float* exp_w1 = (const float*)d_in[5];
    const float* exp_b1 = (const float*)d_in[6];
    const float* exp_w2 = (const float*)d_in[7];
    const float* exp_b2 = (const float*)d_in[8];
    float* out = (float*)d_out;

    // ---- workspace layout (~62 MB), lifetime-based aliasing ----
    char* w = (char*)d_ws;
    float* psum   = (float*)w;              w += (size_t)NB * 16 * 4;
    float* gvalp  = (float*)w;              w += (size_t)NB * 4;
    int* top1     = (int*)w;                w += (size_t)NB * 4;
    int* brows    = (int*)w;                w += (size_t)NB * 4;
    int* ambig_rows = (int*)w;              w += (size_t)NB * 4;
    int* counts   = (int*)w;                w += 16 * 4;
    int* offsets  = (int*)w;                w += 16 * 4;
    int* bpos     = (int*)w;                w += 16 * 4;
    int* ambig_cnt = (int*)w;               w += 4 * 4;
    int* tm_e     = (int*)w;                w += NTILES * 4;
    int* tm_p     = (int*)w;                w += NTILES * 4;
    int* tm_end   = (int*)w;                w += NTILES * 4;
    w = (char*)(((size_t)w + 15) & ~(size_t)15);
    unsigned short* qhi  = (unsigned short*)w;  w += (size_t)NB * H * 2;   // lives whole pipeline
    unsigned short* qlo  = (unsigned short*)w;  w += (size_t)NB * H * 2;   // dead after g1 -> ew2b
    unsigned short* x1hi = (unsigned short*)w;                              // dead after logits
    unsigned short* x1lo = x1hi + (size_t)NB * HH;  w += (size_t)NB * HH * 2 * 2;  // -> ew1b
    unsigned short* hbuf = (unsigned short*)w;  w += (size_t)NB * HH * 2;
    unsigned short* w1hi = (unsigned short*)w;  w += (size_t)HH * H * 2;
    unsigned short* w1lo = (unsigned short*)w;  w += (size_t)HH * H * 2;
    unsigned short* w3hi = (unsigned short*)w;  w += (size_t)NEXP * HH * 2;
    unsigned short* w3lo = (unsigned short*)w;  w += (size_t)NEXP * HH * 2;
    unsigned short* ew1b = x1hi;   // reused after logits
    unsigned short* ew2b = qlo;    // reused after g1

    cvtA_kernel<<<8712, 256, 0, stream>>>(q, cls1_w, cls3_w, qhi, qlo, w1hi, w1lo,
                                          w3hi, w3lo, counts, ambig_cnt);
    g1_kernel<<<dim3(NB / 32, 8), 64, 0, stream>>>(qhi, qlo, w1hi, w1lo, cls1_b, x1hi, x1lo);
    logits_kernel<<<NB / 32, 256, 0, stream>>>(x1hi, x1lo, w3hi, w3lo, cls3_b,
                                               top1, gvalp, counts, ambig_rows, ambig_cnt);
    fixup_kernel<<<256, 256, 0, stream>>>(q, cls1_w, cls1_b, cls3_w, cls3_b,
                                          ambig_rows, ambig_cnt, top1, gvalp, counts);
    cvtB_kernel<<<16384, 256, 0, stream>>>(exp_w1, exp_w2, ew1b, ew2b);
    offsets_kernel<<<1, 64, 0, stream>>>(counts, offsets, bpos, tm_e, tm_p, tm_end);
    scatter_kernel<<<NB / 256, 256, 0, stream>>>(top1, bpos, brows);
    exp1_kernel<<<dim3(NTILES, 8), 64, 0, stream>>>(qhi, ew1b, exp_b1,
                                                    tm_e, tm_p, tm_end, brows, hbuf);
    exp2_kernel<<<dim3(NTILES, 16), 64, 0, stream>>>(hbuf, ew2b, exp_b2,
                                                     tm_e, tm_p, tm_end, brows, out, psum);
    finalize_kernel<<<NB, 256, 0, stream>>>(out, q, psum, gvalp);
}